// Round 17
// baseline (618.825 us; speedup 1.0000x reference)
//
#include <hip/hip_runtime.h>

#define NE 800000
#define NN 50000
#define NG 256

typedef unsigned short us;
typedef us us4 __attribute__((ext_vector_type(4)));
typedef us us8 __attribute__((ext_vector_type(8)));
typedef __bf16 bf16x8 __attribute__((ext_vector_type(8)));
typedef float f32x4 __attribute__((ext_vector_type(4)));

__device__ __forceinline__ float bf2f(us v) {
    unsigned int u = ((unsigned int)v) << 16;
    return __builtin_bit_cast(float, u);
}
__device__ __forceinline__ us f2bf(float f) {
    unsigned int u = __builtin_bit_cast(unsigned int, f);
    u += 0x7fffu + ((u >> 16) & 1u);
    return (us)(u >> 16);
}
__device__ __forceinline__ f32x4 mfma16(us8 a, us8 b, f32x4 c) {
    return __builtin_amdgcn_mfma_f32_16x16x32_bf16(
        __builtin_bit_cast(bf16x8, a), __builtin_bit_cast(bf16x8, b), c, 0, 0, 0);
}
__device__ __forceinline__ us8 ld8(const us* p) { return *(const us8*)p; }
__device__ __forceinline__ us8 cvt8(const float* src) {
    f32x4 v0 = *(const f32x4*)src;
    f32x4 v1 = *(const f32x4*)(src + 4);
    us8 p;
#pragma unroll
    for (int q = 0; q < 4; ++q) { p[q] = f2bf(v0[q]); p[4 + q] = f2bf(v1[q]); }
    return p;
}

// ---------------------------------------------------------------- weight pre-pack (fragment order)
__global__ __launch_bounds__(512) void pack_kernel(
    const float* __restrict__ e_w1, const float* __restrict__ e_w2,
    const float* __restrict__ n1_w1, const float* __restrict__ n1_w2,
    const float* __restrict__ n2_w1, const float* __restrict__ n2_w2,
    us* __restrict__ packs)
{
    int f = blockIdx.x;
    int t = threadIdx.x;
    int l = t >> 3, i = t & 7;
    int hk = l >> 4, c16 = l & 15;
    float v = 0.f;
    if (f < 48) {            // e_w1 [176x128] pad192: f = w*12 + kt*2 + nt
        int w = f / 12, r = f % 12, kt = r >> 1, nt = r & 1;
        int k = kt * 32 + hk * 8 + i, col = w * 32 + nt * 16 + c16;
        if (k < 176) v = e_w1[k * 128 + col];
    } else if (f < 64) {     // e_w2 [128x64]: f-48 = w*4 + kt
        int g = f - 48, w = g >> 2, kt = g & 3;
        int k = kt * 32 + hk * 8 + i, col = w * 16 + c16;
        v = e_w2[k * 64 + col];
    } else if (f < 96) {     // n1_w1 [128x128]: f-64 = w*8 + kt*2 + nt
        int g = f - 64, w = g >> 3, r = g & 7, kt = r >> 1, nt = r & 1;
        int k = kt * 32 + hk * 8 + i, col = w * 32 + nt * 16 + c16;
        v = n1_w1[k * 128 + col];
    } else if (f < 128) {    // n1_w2 [128x128]
        int g = f - 96, w = g >> 3, r = g & 7, kt = r >> 1, nt = r & 1;
        int k = kt * 32 + hk * 8 + i, col = w * 32 + nt * 16 + c16;
        v = n1_w2[k * 128 + col];
    } else if (f < 184) {    // n2_w1 [208x128] pad224: f-128 = w*14 + kt*2 + nt
        int g = f - 128, w = g / 14, r = g % 14, kt = r >> 1, nt = r & 1;
        int k = kt * 32 + hk * 8 + i, col = w * 32 + nt * 16 + c16;
        if (k < 208) v = n2_w1[k * 128 + col];
    } else {                 // n2_w2 [128x64]: f-184 = w*4 + kt
        int g = f - 184, w = g >> 2, kt = g & 3;
        int k = kt * 32 + hk * 8 + i, col = w * 16 + c16;
        v = n2_w2[k * 64 + col];
    }
    packs[f * 512 + l * 8 + i] = f2bf(v);
}

// ---------------------------------------------------------------- prep: bf16 x/u tables + histograms
__global__ __launch_bounds__(256) void prep_kernel(
    const float* __restrict__ x, const float* __restrict__ uu,
    const int* __restrict__ eidx, const int* __restrict__ batch,
    us* __restrict__ xbf, us* __restrict__ ubf,
    int* __restrict__ deg, int* __restrict__ gcount)
{
    int i0 = blockIdx.x * blockDim.x + threadIdx.x;
    int stride = gridDim.x * blockDim.x;
    for (int i = i0; i < NN * 8; i += stride)
        *(us8*)&xbf[(size_t)i * 8] = cvt8(&x[(size_t)i * 8]);
    for (int i = i0; i < NG * 2; i += stride)
        *(us8*)&ubf[(size_t)i * 8] = cvt8(&uu[(size_t)i * 8]);
    for (int e = i0; e < NE; e += stride)
        atomicAdd(&deg[eidx[NE + e]], 1);
    for (int n = i0; n < NN; n += stride) atomicAdd(&gcount[batch[n]], 1);
}

// ---------------------------------------------------------------- parallel scan (3 kernels)
#define NB 49   // ceil(NN/1024)
__global__ __launch_bounds__(1024) void scanA_kernel(const int* __restrict__ deg,
                                                     int* __restrict__ btot) {
    __shared__ int sh[1024];
    int b = blockIdx.x, t = threadIdx.x;
    int idx = b * 1024 + t;
    sh[t] = (idx < NN) ? deg[idx] : 0;
    __syncthreads();
    for (int off = 512; off > 0; off >>= 1) {
        if (t < off) sh[t] += sh[t + off];
        __syncthreads();
    }
    if (t == 0) btot[b] = sh[0];
}

__global__ __launch_bounds__(256) void scanB_kernel(const int* __restrict__ btot,
                                                    const int* __restrict__ gcount,
                                                    int* __restrict__ boff,
                                                    int* __restrict__ graphoff) {
    __shared__ int sb[256];
    __shared__ int sg[256];
    int t = threadIdx.x;
    int bO = (t < NB) ? btot[t] : 0;
    int gO = gcount[t];
    sb[t] = bO;
    sg[t] = gO;
    __syncthreads();
    for (int off = 1; off < 256; off <<= 1) {
        int vb = (t >= off) ? sb[t - off] : 0;
        int vg = (t >= off) ? sg[t - off] : 0;
        __syncthreads();
        sb[t] += vb;
        sg[t] += vg;
        __syncthreads();
    }
    if (t < NB) boff[t] = sb[t] - bO;       // exclusive
    graphoff[t] = sg[t] - gO;                // exclusive
    if (t == 255) graphoff[NG] = sg[255];
}

__global__ __launch_bounds__(1024) void scanC_kernel(const int* __restrict__ deg,
                                                     const int* __restrict__ boff,
                                                     int* __restrict__ cursor) {
    __shared__ int sh[1024];
    int b = blockIdx.x, t = threadIdx.x;
    int idx = b * 1024 + t;
    int v = (idx < NN) ? deg[idx] : 0;
    sh[t] = v;
    __syncthreads();
    for (int off = 1; off < 1024; off <<= 1) {
        int u = (t >= off) ? sh[t - off] : 0;
        __syncthreads();
        sh[t] += u;
        __syncthreads();
    }
    if (idx < NN) cursor[idx] = boff[b] + sh[t] - v;   // exclusive prefix
}

// ---------------------------------------------------------------- CSR scatter + fused ea permute
// rec[p] = {src, dst, eorig, batch[src]}; ea_s[p*32..] = bf16(ea[e*32..]) (64B full line)
__global__ void scatter_kernel(const int* __restrict__ eidx, const int* __restrict__ batch,
                               const float* __restrict__ ea, int* __restrict__ cursor,
                               int4* __restrict__ rec, us* __restrict__ ea_s) {
    int i = blockIdx.x * blockDim.x + threadIdx.x;
    int stride = gridDim.x * blockDim.x;
    for (int e = i; e < NE; e += stride) {
        int s = eidx[e];
        int d = eidx[NE + e];
        int p = atomicAdd(&cursor[d], 1);
        int4 r; r.x = s; r.y = d; r.z = e; r.w = batch[s];
        rec[p] = r;
        if (ea_s) {
            us8 o0 = cvt8(&ea[(size_t)e * 32]);
            us8 o1 = cvt8(&ea[(size_t)e * 32 + 8]);
            us8 o2 = cvt8(&ea[(size_t)e * 32 + 16]);
            us8 o3 = cvt8(&ea[(size_t)e * 32 + 24]);
            us8* dst = (us8*)&ea_s[(size_t)p * 32];
            dst[0] = o0; dst[1] = o1; dst[2] = o2; dst[3] = o3;
        }
    }
}

// ---------------------------------------------------------------- fused edge+message (dst-sorted)
// A1 cols: 0..63 x_src | 64..127 x_dst | 128..159 ea | 160..175 u | 176..191 pad(0) | EB overlays 128..191 after G1
// G4 does register-level segmented reduce (4 consecutive rows per lane) -> direct fp32 atomics; no LDS round-trip.
__global__ __launch_bounds__(256, 3) void edge_kernel(
    const us* __restrict__ xbf, const float* __restrict__ ea, const us* __restrict__ ubf,
    const float* __restrict__ e_b1, const float* __restrict__ e_b2,
    const float* __restrict__ n1_b1, const float* __restrict__ n1_b2,
    const int4* __restrict__ rec, const us* __restrict__ ea_s,
    const us* __restrict__ packs,
    float* __restrict__ out_e, float* __restrict__ aggsum)
{
    __shared__ us A1[64][200];
    __shared__ us H [64][136];
    __shared__ int dstL[64];
    __shared__ int eL[64];

    const int tid = threadIdx.x;
    const int w = tid >> 6, l = tid & 63, hk = l >> 4, c16 = l & 15;

    us8 w1f[6][2], w2f[4], m1f[4][2], m2f[4][2];
#pragma unroll
    for (int kt = 0; kt < 6; ++kt)
#pragma unroll
        for (int nt = 0; nt < 2; ++nt)
            w1f[kt][nt] = ld8(&packs[(size_t)((w * 12 + kt * 2 + nt) * 512 + l * 8)]);
#pragma unroll
    for (int kt = 0; kt < 4; ++kt)
        w2f[kt] = ld8(&packs[(size_t)((48 + w * 4 + kt) * 512 + l * 8)]);
#pragma unroll
    for (int kt = 0; kt < 4; ++kt)
#pragma unroll
        for (int nt = 0; nt < 2; ++nt) {
            m1f[kt][nt] = ld8(&packs[(size_t)((64 + w * 8 + kt * 2 + nt) * 512 + l * 8)]);
            m2f[kt][nt] = ld8(&packs[(size_t)((96 + w * 8 + kt * 2 + nt) * 512 + l * 8)]);
        }

    const float b1v0  = e_b1[w * 32 + c16];
    const float b1v1  = e_b1[w * 32 + 16 + c16];
    const float b2v   = e_b2[w * 16 + c16];
    const float nb1v0 = n1_b1[w * 32 + c16];
    const float nb1v1 = n1_b1[w * 32 + 16 + c16];
    const float nb2v0 = n1_b2[w * 32 + c16];
    const float nb2v1 = n1_b2[w * 32 + 16 + c16];

    for (int it = blockIdx.x; it < NE / 64; it += gridDim.x) {
        const int e0 = it * 64;
        const int4* rt = &rec[e0];

        // ---- stage (rewrites ea/u + re-zeros pad each tile; EB overlay dirtied 128..191) ----
        {
            const int e = tid >> 3, ch = tid & 7;
            int4 r0 = rt[e];
            int4 r1 = rt[e + 32];
            *(us8*)&A1[e][ch * 8]           = ld8(&xbf[(size_t)r0.x * 64 + ch * 8]);
            *(us8*)&A1[e + 32][ch * 8]      = ld8(&xbf[(size_t)r1.x * 64 + ch * 8]);
            *(us8*)&A1[e][64 + ch * 8]      = ld8(&xbf[(size_t)r0.y * 64 + ch * 8]);
            *(us8*)&A1[e + 32][64 + ch * 8] = ld8(&xbf[(size_t)r1.y * 64 + ch * 8]);
            if (ea_s) {
                int e2 = tid >> 2, c2 = tid & 3;
                *(us8*)&A1[e2][128 + c2 * 8] = ld8(&ea_s[((size_t)e0 + e2) * 32 + c2 * 8]);
            } else {
                f32x4 v0 = *(const f32x4*)&ea[(size_t)r0.z * 32 + ch * 4];
                f32x4 v1 = *(const f32x4*)&ea[(size_t)r1.z * 32 + ch * 4];
                us4 p0, p1;
#pragma unroll
                for (int qq = 0; qq < 4; ++qq) { p0[qq] = f2bf(v0[qq]); p1[qq] = f2bf(v1[qq]); }
                *(us4*)&A1[e][128 + ch * 4]      = p0;
                *(us4*)&A1[e + 32][128 + ch * 4] = p1;
            }
        }
        if (tid < 128) {                                   // u rows + pad re-zero
            int e = tid >> 1, ch = tid & 1;
            *(us8*)&A1[e][160 + ch * 8] = ld8(&ubf[rt[e].w * 16 + ch * 8]);
            us8 z = {0, 0, 0, 0, 0, 0, 0, 0};
            *(us8*)&A1[e][176 + ch * 8] = z;
        } else if (tid < 192) {
            dstL[tid - 128] = rt[tid - 128].y;
        } else {
            eL[tid - 192] = rt[tid - 192].z;
        }
        __syncthreads();

        // ---- G1: H = relu(A1 @ e_w1 + b1) ----
#pragma unroll
        for (int mt = 0; mt < 4; ++mt) {
            f32x4 a0 = {0.f, 0.f, 0.f, 0.f}, a1 = {0.f, 0.f, 0.f, 0.f};
#pragma unroll
            for (int kt = 0; kt < 6; ++kt) {
                us8 a = ld8(&A1[mt * 16 + c16][kt * 32 + hk * 8]);
                a0 = mfma16(a, w1f[kt][0], a0);
                a1 = mfma16(a, w1f[kt][1], a1);
            }
#pragma unroll
            for (int j = 0; j < 4; ++j) {
                int row = mt * 16 + hk * 4 + j;
                H[row][w * 32 + c16]      = f2bf(fmaxf(a0[j] + b1v0, 0.f));
                H[row][w * 32 + 16 + c16] = f2bf(fmaxf(a1[j] + b1v1, 0.f));
            }
        }
        __syncthreads();

        // ---- G2: edge_new -> out_e (scatter via eL) + EB overlay at A1 cols 128..191 ----
#pragma unroll
        for (int mt = 0; mt < 4; ++mt) {
            f32x4 a0 = {0.f, 0.f, 0.f, 0.f};
#pragma unroll
            for (int kt = 0; kt < 4; ++kt) {
                us8 a = ld8(&H[mt * 16 + c16][kt * 32 + hk * 8]);
                a0 = mfma16(a, w2f[kt], a0);
            }
#pragma unroll
            for (int j = 0; j < 4; ++j) {
                int row = mt * 16 + hk * 4 + j;
                float val = a0[j] + b2v;
                A1[row][128 + w * 16 + c16] = f2bf(val);
                out_e[(size_t)eL[row] * 64 + w * 16 + c16] = val;
            }
        }
        __syncthreads();

        // ---- G3: H = relu([x_src | EB] @ n1_w1 + b1) ----
#pragma unroll
        for (int mt = 0; mt < 4; ++mt) {
            f32x4 a0 = {0.f, 0.f, 0.f, 0.f}, a1 = {0.f, 0.f, 0.f, 0.f};
#pragma unroll
            for (int kt = 0; kt < 4; ++kt) {
                us8 a = (kt < 2) ? ld8(&A1[mt * 16 + c16][kt * 32 + hk * 8])
                                 : ld8(&A1[mt * 16 + c16][128 + (kt - 2) * 32 + hk * 8]);
                a0 = mfma16(a, m1f[kt][0], a0);
                a1 = mfma16(a, m1f[kt][1], a1);
            }
#pragma unroll
            for (int j = 0; j < 4; ++j) {
                int row = mt * 16 + hk * 4 + j;
                H[row][w * 32 + c16]      = f2bf(fmaxf(a0[j] + nb1v0, 0.f));
                H[row][w * 32 + 16 + c16] = f2bf(fmaxf(a1[j] + nb1v1, 0.f));
            }
        }
        __syncthreads();

        // ---- G4: m in registers -> register-level segmented reduce -> fp32 atomics ----
        // lane's 4 rows (r0 = mt*16+hk*4 .. +3) are CONSECUTIVE in the dst-sorted order.
#pragma unroll
        for (int mt = 0; mt < 4; ++mt) {
            f32x4 a0 = {0.f, 0.f, 0.f, 0.f}, a1 = {0.f, 0.f, 0.f, 0.f};
#pragma unroll
            for (int kt = 0; kt < 4; ++kt) {
                us8 a = ld8(&H[mt * 16 + c16][kt * 32 + hk * 8]);
                a0 = mfma16(a, m2f[kt][0], a0);
                a1 = mfma16(a, m2f[kt][1], a1);
            }
            const int r0 = mt * 16 + hk * 4;
            int4 dv = *(const int4*)&dstL[r0];       // b128 LDS read, 16B-aligned
            float s0 = a0[0] + nb2v0;
            float s1 = a1[0] + nb2v1;
            int cur = dv.x;
            int dnext[3] = {dv.y, dv.z, dv.w};
#pragma unroll
            for (int j = 1; j < 4; ++j) {
                float v0 = a0[j] + nb2v0;
                float v1 = a1[j] + nb2v1;
                int d = dnext[j - 1];
                if (d != cur) {
                    atomicAdd(&aggsum[(size_t)cur * 128 + w * 32 + c16],      s0);
                    atomicAdd(&aggsum[(size_t)cur * 128 + w * 32 + 16 + c16], s1);
                    cur = d; s0 = v0; s1 = v1;
                } else {
                    s0 += v0; s1 += v1;
                }
            }
            atomicAdd(&aggsum[(size_t)cur * 128 + w * 32 + c16],      s0);
            atomicAdd(&aggsum[(size_t)cur * 128 + w * 32 + 16 + c16], s1);
        }
        __syncthreads();   // protect H (next G1 writes) + dstL/eL/A1 (next stage writes)
    }
}

// ---------------------------------------------------------------- node update (reads xbf)
__global__ __launch_bounds__(256, 3) void node_kernel(
    const us* __restrict__ xbf, const float* __restrict__ uu,
    const float* __restrict__ n2_b1, const float* __restrict__ n2_b2,
    const int* __restrict__ batch,
    const float* __restrict__ aggsum, const int* __restrict__ deg,
    const us* __restrict__ packs, float* __restrict__ out_x)
{
    __shared__ us A3[64][232];
    __shared__ us H3[64][136];

    const int tid = threadIdx.x;
    const int w = tid >> 6, l = tid & 63, hk = l >> 4, c16 = l & 15;

    for (int i = tid; i < 64 * 16; i += 256)
        A3[i >> 4][208 + (i & 15)] = 0;

    us8 w1f[7][2], w2f[4];
#pragma unroll
    for (int kt = 0; kt < 7; ++kt)
#pragma unroll
        for (int nt = 0; nt < 2; ++nt)
            w1f[kt][nt] = ld8(&packs[(size_t)((128 + w * 14 + kt * 2 + nt) * 512 + l * 8)]);
#pragma unroll
    for (int kt = 0; kt < 4; ++kt)
        w2f[kt] = ld8(&packs[(size_t)((184 + w * 4 + kt) * 512 + l * 8)]);

    const float b1v0 = n2_b1[w * 32 + c16];
    const float b1v1 = n2_b1[w * 32 + 16 + c16];
    const float b2v  = n2_b2[w * 16 + c16];

    const int niter = (NN + 63) / 64;
    for (int it = blockIdx.x; it < niter; it += gridDim.x) {
        const int n0 = it * 64;
        for (int i = tid; i < 64 * 26; i += 256) {
            int n  = i / 26;
            int ch = i - n * 26;
            int gn = n0 + n;
            us8 v = {0, 0, 0, 0, 0, 0, 0, 0};
            if (gn < NN) {
                if (ch < 8) {
                    v = ld8(&xbf[(size_t)gn * 64 + ch * 8]);
                } else if (ch < 24) {
                    int cc = (ch - 8) * 8;
                    float inv = 1.0f / fmaxf((float)deg[gn], 1.0f);
                    const float* ap = &aggsum[(size_t)gn * 128 + cc];
                    us8 t;
#pragma unroll
                    for (int q = 0; q < 8; ++q) t[q] = f2bf(ap[q] * inv);
                    v = t;
                } else {
                    v = cvt8(&uu[(size_t)batch[gn] * 16 + (ch - 24) * 8]);
                }
            }
            *(us8*)&A3[n][ch * 8] = v;
        }
        __syncthreads();

#pragma unroll
        for (int mt = 0; mt < 4; ++mt) {
            f32x4 a0 = {0.f, 0.f, 0.f, 0.f}, a1 = {0.f, 0.f, 0.f, 0.f};
#pragma unroll
            for (int kt = 0; kt < 7; ++kt) {
                us8 a = ld8(&A3[mt * 16 + c16][kt * 32 + hk * 8]);
                a0 = mfma16(a, w1f[kt][0], a0);
                a1 = mfma16(a, w1f[kt][1], a1);
            }
#pragma unroll
            for (int j = 0; j < 4; ++j) {
                int row = mt * 16 + hk * 4 + j;
                H3[row][w * 32 + c16]      = f2bf(fmaxf(a0[j] + b1v0, 0.f));
                H3[row][w * 32 + 16 + c16] = f2bf(fmaxf(a1[j] + b1v1, 0.f));
            }
        }
        __syncthreads();

#pragma unroll
        for (int mt = 0; mt < 4; ++mt) {
            f32x4 a0 = {0.f, 0.f, 0.f, 0.f};
#pragma unroll
            for (int kt = 0; kt < 4; ++kt) {
                us8 a = ld8(&H3[mt * 16 + c16][kt * 32 + hk * 8]);
                a0 = mfma16(a, w2f[kt], a0);
            }
#pragma unroll
            for (int j = 0; j < 4; ++j) {
                int row = mt * 16 + hk * 4 + j;
                int gn  = n0 + row;
                if (gn < NN)
                    out_x[(size_t)gn * 64 + w * 16 + c16] = a0[j] + b2v;
            }
        }
        __syncthreads();
    }
}

// ---------------------------------------------------------------- global update (fp32)
__global__ __launch_bounds__(128) void global_kernel(
    const float* __restrict__ uu,
    const float* __restrict__ g_w1, const float* __restrict__ g_b1,
    const float* __restrict__ g_w2, const float* __restrict__ g_b2,
    const float* __restrict__ out_x, const int* __restrict__ graphoff,
    float* __restrict__ out_u)
{
    const int g = blockIdx.x;
    const int t = threadIdx.x;
    __shared__ float gin[80];
    __shared__ float red[128];
    __shared__ float h[128];
    const int beg = graphoff[g], end = graphoff[g + 1];
    const int col = t & 63, half = t >> 6;
    float acc = 0.f;
    for (int n = beg + half; n < end; n += 2) acc += out_x[(size_t)n * 64 + col];
    red[t] = acc;
    __syncthreads();
    if (t < 64) {
        float c = fmaxf((float)(end - beg), 1.0f);
        gin[16 + t] = (red[t] + red[t + 64]) / c;
    } else if (t >= 112) {
        gin[t - 112] = uu[g * 16 + (t - 112)];
    }
    __syncthreads();
    float a = g_b1[t];
    for (int k = 0; k < 80; ++k) a += gin[k] * g_w1[k * 128 + t];
    h[t] = fmaxf(a, 0.f);
    __syncthreads();
    if (t < 32) {
        float a2 = g_b2[t];
        for (int k = 0; k < 128; ++k) a2 += h[k] * g_w2[k * 32 + t];
        out_u[g * 32 + t] = a2;
    }
}

extern "C" void kernel_launch(void* const* d_in, const int* in_sizes, int n_in,
                              void* d_out, int out_size, void* d_ws, size_t ws_size,
                              hipStream_t stream)
{
    const float* x     = (const float*)d_in[0];
    const float* ea    = (const float*)d_in[1];
    const float* uu    = (const float*)d_in[2];
    const float* e_w1  = (const float*)d_in[3];
    const float* e_b1  = (const float*)d_in[4];
    const float* e_w2  = (const float*)d_in[5];
    const float* e_b2  = (const float*)d_in[6];
    const float* n1_w1 = (const float*)d_in[7];
    const float* n1_b1 = (const float*)d_in[8];
    const float* n1_w2 = (const float*)d_in[9];
    const float* n1_b2 = (const float*)d_in[10];
    const float* n2_w1 = (const float*)d_in[11];
    const float* n2_b1 = (const float*)d_in[12];
    const float* n2_w2 = (const float*)d_in[13];
    const float* n2_b2 = (const float*)d_in[14];
    const float* g_w1  = (const float*)d_in[15];
    const float* g_b1  = (const float*)d_in[16];
    const float* g_w2  = (const float*)d_in[17];
    const float* g_b2  = (const float*)d_in[18];
    const int* eidx  = (const int*)d_in[19];
    const int* batch = (const int*)d_in[20];

    float* out_x = (float*)d_out;
    float* out_e = out_x + (size_t)NN * 64;
    float* out_u = out_e + (size_t)NE * 64;

    // ws: aggsum f32[NN*128] | deg[NN] | gcount[NG] | cursor[NN] | graphoff[260] |
    //     btot[64] | boff[64] | rec int4[NE] | xbf us[NN*64] | ubf us[NG*16] |
    //     packs us[200*512] | [ea_s us[NE*32] gated]
    float* aggsum   = (float*)d_ws;
    int*   deg      = (int*)(aggsum + (size_t)NN * 128);
    int*   gcount   = deg + NN;
    int*   cursor   = gcount + NG;
    int*   graphoff = cursor + NN;
    int*   btot     = graphoff + 260;
    int*   boff     = btot + 64;
    int4*  rec      = (int4*)(boff + 64);     // byte offset divisible by 16
    us*    xbf      = (us*)(rec + NE);
    us*    ubf      = xbf + (size_t)NN * 64;
    us*    packs    = ubf + (size_t)NG * 16;
    us*    wend     = packs + (size_t)200 * 512;
    size_t used     = (size_t)((char*)wend - (char*)d_ws);
    us* ea_s = nullptr;
    if (used + (size_t)NE * 32 * 2 <= ws_size) ea_s = wend;

    size_t zbytes = (size_t)NN * 128 * sizeof(float) + (NN + NG) * sizeof(int);
    hipMemsetAsync(d_ws, 0, zbytes, stream);

    hipLaunchKernelGGL(pack_kernel, dim3(200), dim3(512), 0, stream,
        e_w1, e_w2, n1_w1, n1_w2, n2_w1, n2_w2, packs);
    hipLaunchKernelGGL(prep_kernel, dim3(512), dim3(256), 0, stream,
        x, uu, eidx, batch, xbf, ubf, deg, gcount);
    hipLaunchKernelGGL(scanA_kernel, dim3(NB), dim3(1024), 0, stream, deg, btot);
    hipLaunchKernelGGL(scanB_kernel, dim3(1), dim3(256), 0, stream,
        btot, gcount, boff, graphoff);
    hipLaunchKernelGGL(scanC_kernel, dim3(NB), dim3(1024), 0, stream, deg, boff, cursor);
    hipLaunchKernelGGL(scatter_kernel, dim3(1024), dim3(256), 0, stream,
        eidx, batch, ea, cursor, rec, ea_s);
    hipLaunchKernelGGL(edge_kernel, dim3(768), dim3(256), 0, stream,
        xbf, ea, ubf, e_b1, e_b2, n1_b1, n1_b2, rec, ea_s, packs, out_e, aggsum);
    hipLaunchKernelGGL(node_kernel, dim3(782), dim3(256), 0, stream,
        xbf, uu, n2_b1, n2_b2, batch, aggsum, deg, packs, out_x);
    hipLaunchKernelGGL(global_kernel, dim3(NG), dim3(128), 0, stream,
        uu, g_w1, g_b1, g_w2, g_b2, out_x, graphoff, out_u);
}

// Round 18
// 454.693 us; speedup vs baseline: 1.3610x; 1.3610x over previous
//
#include <hip/hip_runtime.h>

#define NE 800000
#define NN 50000
#define NG 256

typedef unsigned short us;
typedef us us4 __attribute__((ext_vector_type(4)));
typedef us us8 __attribute__((ext_vector_type(8)));
typedef __bf16 bf16x8 __attribute__((ext_vector_type(8)));
typedef float f32x4 __attribute__((ext_vector_type(4)));

__device__ __forceinline__ float bf2f(us v) {
    unsigned int u = ((unsigned int)v) << 16;
    return __builtin_bit_cast(float, u);
}
__device__ __forceinline__ us f2bf(float f) {
    unsigned int u = __builtin_bit_cast(unsigned int, f);
    u += 0x7fffu + ((u >> 16) & 1u);
    return (us)(u >> 16);
}
__device__ __forceinline__ f32x4 mfma16(us8 a, us8 b, f32x4 c) {
    return __builtin_amdgcn_mfma_f32_16x16x32_bf16(
        __builtin_bit_cast(bf16x8, a), __builtin_bit_cast(bf16x8, b), c, 0, 0, 0);
}
__device__ __forceinline__ us8 ld8(const us* p) { return *(const us8*)p; }
__device__ __forceinline__ us8 cvt8(const float* src) {
    f32x4 v0 = *(const f32x4*)src;
    f32x4 v1 = *(const f32x4*)(src + 4);
    us8 p;
#pragma unroll
    for (int q = 0; q < 4; ++q) { p[q] = f2bf(v0[q]); p[4 + q] = f2bf(v1[q]); }
    return p;
}

// ---------------------------------------------------------------- weight pre-pack (fragment order)
__global__ __launch_bounds__(512) void pack_kernel(
    const float* __restrict__ e_w1, const float* __restrict__ e_w2,
    const float* __restrict__ n1_w1, const float* __restrict__ n1_w2,
    const float* __restrict__ n2_w1, const float* __restrict__ n2_w2,
    us* __restrict__ packs)
{
    int f = blockIdx.x;
    int t = threadIdx.x;
    int l = t >> 3, i = t & 7;
    int hk = l >> 4, c16 = l & 15;
    float v = 0.f;
    if (f < 48) {            // e_w1 [176x128] pad192: f = w*12 + kt*2 + nt
        int w = f / 12, r = f % 12, kt = r >> 1, nt = r & 1;
        int k = kt * 32 + hk * 8 + i, col = w * 32 + nt * 16 + c16;
        if (k < 176) v = e_w1[k * 128 + col];
    } else if (f < 64) {     // e_w2 [128x64]: f-48 = w*4 + kt
        int g = f - 48, w = g >> 2, kt = g & 3;
        int k = kt * 32 + hk * 8 + i, col = w * 16 + c16;
        v = e_w2[k * 64 + col];
    } else if (f < 96) {     // n1_w1 [128x128]: f-64 = w*8 + kt*2 + nt
        int g = f - 64, w = g >> 3, r = g & 7, kt = r >> 1, nt = r & 1;
        int k = kt * 32 + hk * 8 + i, col = w * 32 + nt * 16 + c16;
        v = n1_w1[k * 128 + col];
    } else if (f < 128) {    // n1_w2 [128x128]
        int g = f - 96, w = g >> 3, r = g & 7, kt = r >> 1, nt = r & 1;
        int k = kt * 32 + hk * 8 + i, col = w * 32 + nt * 16 + c16;
        v = n1_w2[k * 128 + col];
    } else if (f < 184) {    // n2_w1 [208x128] pad224: f-128 = w*14 + kt*2 + nt
        int g = f - 128, w = g / 14, r = g % 14, kt = r >> 1, nt = r & 1;
        int k = kt * 32 + hk * 8 + i, col = w * 32 + nt * 16 + c16;
        if (k < 208) v = n2_w1[k * 128 + col];
    } else {                 // n2_w2 [128x64]: f-184 = w*4 + kt
        int g = f - 184, w = g >> 2, kt = g & 3;
        int k = kt * 32 + hk * 8 + i, col = w * 16 + c16;
        v = n2_w2[k * 64 + col];
    }
    packs[f * 512 + l * 8 + i] = f2bf(v);
}

// ---------------------------------------------------------------- prep: bf16 x/u tables + histograms
__global__ __launch_bounds__(256) void prep_kernel(
    const float* __restrict__ x, const float* __restrict__ uu,
    const int* __restrict__ eidx, const int* __restrict__ batch,
    us* __restrict__ xbf, us* __restrict__ ubf,
    int* __restrict__ deg, int* __restrict__ gcount)
{
    int i0 = blockIdx.x * blockDim.x + threadIdx.x;
    int stride = gridDim.x * blockDim.x;
    for (int i = i0; i < NN * 8; i += stride)
        *(us8*)&xbf[(size_t)i * 8] = cvt8(&x[(size_t)i * 8]);
    for (int i = i0; i < NG * 2; i += stride)
        *(us8*)&ubf[(size_t)i * 8] = cvt8(&uu[(size_t)i * 8]);
    for (int e = i0; e < NE; e += stride)
        atomicAdd(&deg[eidx[NE + e]], 1);
    for (int n = i0; n < NN; n += stride) atomicAdd(&gcount[batch[n]], 1);
}

// ---------------------------------------------------------------- parallel scan (3 kernels)
#define NB 49   // ceil(NN/1024)
__global__ __launch_bounds__(1024) void scanA_kernel(const int* __restrict__ deg,
                                                     int* __restrict__ btot) {
    __shared__ int sh[1024];
    int b = blockIdx.x, t = threadIdx.x;
    int idx = b * 1024 + t;
    sh[t] = (idx < NN) ? deg[idx] : 0;
    __syncthreads();
    for (int off = 512; off > 0; off >>= 1) {
        if (t < off) sh[t] += sh[t + off];
        __syncthreads();
    }
    if (t == 0) btot[b] = sh[0];
}

__global__ __launch_bounds__(256) void scanB_kernel(const int* __restrict__ btot,
                                                    const int* __restrict__ gcount,
                                                    int* __restrict__ boff,
                                                    int* __restrict__ graphoff) {
    __shared__ int sb[256];
    __shared__ int sg[256];
    int t = threadIdx.x;
    int bO = (t < NB) ? btot[t] : 0;
    int gO = gcount[t];
    sb[t] = bO;
    sg[t] = gO;
    __syncthreads();
    for (int off = 1; off < 256; off <<= 1) {
        int vb = (t >= off) ? sb[t - off] : 0;
        int vg = (t >= off) ? sg[t - off] : 0;
        __syncthreads();
        sb[t] += vb;
        sg[t] += vg;
        __syncthreads();
    }
    if (t < NB) boff[t] = sb[t] - bO;       // exclusive
    graphoff[t] = sg[t] - gO;                // exclusive
    if (t == 255) graphoff[NG] = sg[255];
}

__global__ __launch_bounds__(1024) void scanC_kernel(const int* __restrict__ deg,
                                                     const int* __restrict__ boff,
                                                     int* __restrict__ cursor) {
    __shared__ int sh[1024];
    int b = blockIdx.x, t = threadIdx.x;
    int idx = b * 1024 + t;
    int v = (idx < NN) ? deg[idx] : 0;
    sh[t] = v;
    __syncthreads();
    for (int off = 1; off < 1024; off <<= 1) {
        int u = (t >= off) ? sh[t - off] : 0;
        __syncthreads();
        sh[t] += u;
        __syncthreads();
    }
    if (idx < NN) cursor[idx] = boff[b] + sh[t] - v;   // exclusive prefix
}

// ---------------------------------------------------------------- CSR scatter + fused ea permute
// rec[p] = {src, dst, eorig, batch[src]}; ea_s[p*32..] = bf16(ea[e*32..]) (64B full line)
__global__ void scatter_kernel(const int* __restrict__ eidx, const int* __restrict__ batch,
                               const float* __restrict__ ea, int* __restrict__ cursor,
                               int4* __restrict__ rec, us* __restrict__ ea_s) {
    int i = blockIdx.x * blockDim.x + threadIdx.x;
    int stride = gridDim.x * blockDim.x;
    for (int e = i; e < NE; e += stride) {
        int s = eidx[e];
        int d = eidx[NE + e];
        int p = atomicAdd(&cursor[d], 1);
        int4 r; r.x = s; r.y = d; r.z = e; r.w = batch[s];
        rec[p] = r;
        if (ea_s) {
            us8 o0 = cvt8(&ea[(size_t)e * 32]);
            us8 o1 = cvt8(&ea[(size_t)e * 32 + 8]);
            us8 o2 = cvt8(&ea[(size_t)e * 32 + 16]);
            us8 o3 = cvt8(&ea[(size_t)e * 32 + 24]);
            us8* dst = (us8*)&ea_s[(size_t)p * 32];
            dst[0] = o0; dst[1] = o1; dst[2] = o2; dst[3] = o3;
        }
    }
}

// ---------------------------------------------------------------- fused edge+message (dst-sorted)
// A1 cols: 0..63 x_src | 64..127 x_dst | 128..159 ea | 160..175 u | 176..191 pad(0) | EB overlays 128..191 after G1
// Strided tile assignment; full __syncthreads barriers; LDS-based segmented reduce (R16-proven).
__global__ __launch_bounds__(256, 3) void edge_kernel(
    const us* __restrict__ xbf, const float* __restrict__ ea, const us* __restrict__ ubf,
    const float* __restrict__ e_b1, const float* __restrict__ e_b2,
    const float* __restrict__ n1_b1, const float* __restrict__ n1_b2,
    const int4* __restrict__ rec, const us* __restrict__ ea_s,
    const us* __restrict__ packs,
    float* __restrict__ out_e, float* __restrict__ aggsum)
{
    __shared__ us A1[64][200];
    __shared__ us H [64][136];
    __shared__ int dstL[64];
    __shared__ int eL[64];

    const int tid = threadIdx.x;
    const int w = tid >> 6, l = tid & 63, hk = l >> 4, c16 = l & 15;

    us8 w1f[6][2], w2f[4], m1f[4][2], m2f[4][2];
#pragma unroll
    for (int kt = 0; kt < 6; ++kt)
#pragma unroll
        for (int nt = 0; nt < 2; ++nt)
            w1f[kt][nt] = ld8(&packs[(size_t)((w * 12 + kt * 2 + nt) * 512 + l * 8)]);
#pragma unroll
    for (int kt = 0; kt < 4; ++kt)
        w2f[kt] = ld8(&packs[(size_t)((48 + w * 4 + kt) * 512 + l * 8)]);
#pragma unroll
    for (int kt = 0; kt < 4; ++kt)
#pragma unroll
        for (int nt = 0; nt < 2; ++nt) {
            m1f[kt][nt] = ld8(&packs[(size_t)((64 + w * 8 + kt * 2 + nt) * 512 + l * 8)]);
            m2f[kt][nt] = ld8(&packs[(size_t)((96 + w * 8 + kt * 2 + nt) * 512 + l * 8)]);
        }

    const float b1v0  = e_b1[w * 32 + c16];
    const float b1v1  = e_b1[w * 32 + 16 + c16];
    const float b2v   = e_b2[w * 16 + c16];
    const float nb1v0 = n1_b1[w * 32 + c16];
    const float nb1v1 = n1_b1[w * 32 + 16 + c16];
    const float nb2v0 = n1_b2[w * 32 + c16];
    const float nb2v1 = n1_b2[w * 32 + 16 + c16];

    for (int it = blockIdx.x; it < NE / 64; it += gridDim.x) {
        const int e0 = it * 64;
        const int4* rt = &rec[e0];

        // ---- stage (rewrites ea/u + re-zeros pad each tile; EB overlay dirtied 128..191) ----
        {
            const int e = tid >> 3, ch = tid & 7;
            int4 r0 = rt[e];
            int4 r1 = rt[e + 32];
            *(us8*)&A1[e][ch * 8]           = ld8(&xbf[(size_t)r0.x * 64 + ch * 8]);
            *(us8*)&A1[e + 32][ch * 8]      = ld8(&xbf[(size_t)r1.x * 64 + ch * 8]);
            *(us8*)&A1[e][64 + ch * 8]      = ld8(&xbf[(size_t)r0.y * 64 + ch * 8]);
            *(us8*)&A1[e + 32][64 + ch * 8] = ld8(&xbf[(size_t)r1.y * 64 + ch * 8]);
            if (ea_s) {
                int e2 = tid >> 2, c2 = tid & 3;
                *(us8*)&A1[e2][128 + c2 * 8] = ld8(&ea_s[((size_t)e0 + e2) * 32 + c2 * 8]);
            } else {
                f32x4 v0 = *(const f32x4*)&ea[(size_t)r0.z * 32 + ch * 4];
                f32x4 v1 = *(const f32x4*)&ea[(size_t)r1.z * 32 + ch * 4];
                us4 p0, p1;
#pragma unroll
                for (int qq = 0; qq < 4; ++qq) { p0[qq] = f2bf(v0[qq]); p1[qq] = f2bf(v1[qq]); }
                *(us4*)&A1[e][128 + ch * 4]      = p0;
                *(us4*)&A1[e + 32][128 + ch * 4] = p1;
            }
        }
        if (tid < 128) {                                   // u rows + pad re-zero
            int e = tid >> 1, ch = tid & 1;
            *(us8*)&A1[e][160 + ch * 8] = ld8(&ubf[rt[e].w * 16 + ch * 8]);
            us8 z = {0, 0, 0, 0, 0, 0, 0, 0};
            *(us8*)&A1[e][176 + ch * 8] = z;
        } else if (tid < 192) {
            dstL[tid - 128] = rt[tid - 128].y;
        } else {
            eL[tid - 192] = rt[tid - 192].z;
        }
        __syncthreads();

        // ---- G1: H = relu(A1 @ e_w1 + b1) ----
#pragma unroll
        for (int mt = 0; mt < 4; ++mt) {
            f32x4 a0 = {0.f, 0.f, 0.f, 0.f}, a1 = {0.f, 0.f, 0.f, 0.f};
#pragma unroll
            for (int kt = 0; kt < 6; ++kt) {
                us8 a = ld8(&A1[mt * 16 + c16][kt * 32 + hk * 8]);
                a0 = mfma16(a, w1f[kt][0], a0);
                a1 = mfma16(a, w1f[kt][1], a1);
            }
#pragma unroll
            for (int j = 0; j < 4; ++j) {
                int row = mt * 16 + hk * 4 + j;
                H[row][w * 32 + c16]      = f2bf(fmaxf(a0[j] + b1v0, 0.f));
                H[row][w * 32 + 16 + c16] = f2bf(fmaxf(a1[j] + b1v1, 0.f));
            }
        }
        __syncthreads();

        // ---- G2: edge_new -> out_e (scatter via eL) + EB overlay at A1 cols 128..191 ----
#pragma unroll
        for (int mt = 0; mt < 4; ++mt) {
            f32x4 a0 = {0.f, 0.f, 0.f, 0.f};
#pragma unroll
            for (int kt = 0; kt < 4; ++kt) {
                us8 a = ld8(&H[mt * 16 + c16][kt * 32 + hk * 8]);
                a0 = mfma16(a, w2f[kt], a0);
            }
#pragma unroll
            for (int j = 0; j < 4; ++j) {
                int row = mt * 16 + hk * 4 + j;
                float val = a0[j] + b2v;
                A1[row][128 + w * 16 + c16] = f2bf(val);
                out_e[(size_t)eL[row] * 64 + w * 16 + c16] = val;
            }
        }
        __syncthreads();

        // ---- G3: H = relu([x_src | EB] @ n1_w1 + b1) ----
#pragma unroll
        for (int mt = 0; mt < 4; ++mt) {
            f32x4 a0 = {0.f, 0.f, 0.f, 0.f}, a1 = {0.f, 0.f, 0.f, 0.f};
#pragma unroll
            for (int kt = 0; kt < 4; ++kt) {
                us8 a = (kt < 2) ? ld8(&A1[mt * 16 + c16][kt * 32 + hk * 8])
                                 : ld8(&A1[mt * 16 + c16][128 + (kt - 2) * 32 + hk * 8]);
                a0 = mfma16(a, m1f[kt][0], a0);
                a1 = mfma16(a, m1f[kt][1], a1);
            }
#pragma unroll
            for (int j = 0; j < 4; ++j) {
                int row = mt * 16 + hk * 4 + j;
                H[row][w * 32 + c16]      = f2bf(fmaxf(a0[j] + nb1v0, 0.f));
                H[row][w * 32 + 16 + c16] = f2bf(fmaxf(a1[j] + nb1v1, 0.f));
            }
        }
        __syncthreads();

        // ---- G4: m -> A1 cols 0..127 (x halves dead after G3) ----
#pragma unroll
        for (int mt = 0; mt < 4; ++mt) {
            f32x4 a0 = {0.f, 0.f, 0.f, 0.f}, a1 = {0.f, 0.f, 0.f, 0.f};
#pragma unroll
            for (int kt = 0; kt < 4; ++kt) {
                us8 a = ld8(&H[mt * 16 + c16][kt * 32 + hk * 8]);
                a0 = mfma16(a, m2f[kt][0], a0);
                a1 = mfma16(a, m2f[kt][1], a1);
            }
#pragma unroll
            for (int j = 0; j < 4; ++j) {
                int row = mt * 16 + hk * 4 + j;
                A1[row][w * 32 + c16]      = f2bf(a0[j] + nb2v0);
                A1[row][w * 32 + 16 + c16] = f2bf(a1[j] + nb2v1);
            }
        }
        __syncthreads();

        // ---- segmented reduce over sorted dst runs ----
        {
            int c = tid & 127, half = tid >> 7, r0 = half * 32;
            float acc = 0.f;
            int cur = dstL[r0];
            for (int rr = r0; rr < r0 + 32; ++rr) {
                int d = dstL[rr];
                float v = bf2f(A1[rr][c]);
                if (d != cur) {
                    atomicAdd(&aggsum[(size_t)cur * 128 + c], acc);
                    cur = d; acc = v;
                } else {
                    acc += v;
                }
            }
            atomicAdd(&aggsum[(size_t)cur * 128 + c], acc);
        }
        __syncthreads();
    }
}

// ---------------------------------------------------------------- node update (reads xbf + ubf)
__global__ __launch_bounds__(256, 3) void node_kernel(
    const us* __restrict__ xbf, const us* __restrict__ ubf,
    const float* __restrict__ n2_b1, const float* __restrict__ n2_b2,
    const int* __restrict__ batch,
    const float* __restrict__ aggsum, const int* __restrict__ deg,
    const us* __restrict__ packs, float* __restrict__ out_x)
{
    __shared__ us A3[64][232];
    __shared__ us H3[64][136];

    const int tid = threadIdx.x;
    const int w = tid >> 6, l = tid & 63, hk = l >> 4, c16 = l & 15;

    for (int i = tid; i < 64 * 16; i += 256)
        A3[i >> 4][208 + (i & 15)] = 0;

    us8 w1f[7][2], w2f[4];
#pragma unroll
    for (int kt = 0; kt < 7; ++kt)
#pragma unroll
        for (int nt = 0; nt < 2; ++nt)
            w1f[kt][nt] = ld8(&packs[(size_t)((128 + w * 14 + kt * 2 + nt) * 512 + l * 8)]);
#pragma unroll
    for (int kt = 0; kt < 4; ++kt)
        w2f[kt] = ld8(&packs[(size_t)((184 + w * 4 + kt) * 512 + l * 8)]);

    const float b1v0 = n2_b1[w * 32 + c16];
    const float b1v1 = n2_b1[w * 32 + 16 + c16];
    const float b2v  = n2_b2[w * 16 + c16];

    const int niter = (NN + 63) / 64;
    for (int it = blockIdx.x; it < niter; it += gridDim.x) {
        const int n0 = it * 64;
        for (int i = tid; i < 64 * 26; i += 256) {
            int n  = i / 26;
            int ch = i - n * 26;
            int gn = n0 + n;
            us8 v = {0, 0, 0, 0, 0, 0, 0, 0};
            if (gn < NN) {
                if (ch < 8) {
                    v = ld8(&xbf[(size_t)gn * 64 + ch * 8]);
                } else if (ch < 24) {
                    int cc = (ch - 8) * 8;
                    float inv = 1.0f / fmaxf((float)deg[gn], 1.0f);
                    const float* ap = &aggsum[(size_t)gn * 128 + cc];
                    us8 t;
#pragma unroll
                    for (int q = 0; q < 8; ++q) t[q] = f2bf(ap[q] * inv);
                    v = t;
                } else {
                    v = ld8(&ubf[(size_t)batch[gn] * 16 + (ch - 24) * 8]);
                }
            }
            *(us8*)&A3[n][ch * 8] = v;
        }
        __syncthreads();

#pragma unroll
        for (int mt = 0; mt < 4; ++mt) {
            f32x4 a0 = {0.f, 0.f, 0.f, 0.f}, a1 = {0.f, 0.f, 0.f, 0.f};
#pragma unroll
            for (int kt = 0; kt < 7; ++kt) {
                us8 a = ld8(&A3[mt * 16 + c16][kt * 32 + hk * 8]);
                a0 = mfma16(a, w1f[kt][0], a0);
                a1 = mfma16(a, w1f[kt][1], a1);
            }
#pragma unroll
            for (int j = 0; j < 4; ++j) {
                int row = mt * 16 + hk * 4 + j;
                H3[row][w * 32 + c16]      = f2bf(fmaxf(a0[j] + b1v0, 0.f));
                H3[row][w * 32 + 16 + c16] = f2bf(fmaxf(a1[j] + b1v1, 0.f));
            }
        }
        __syncthreads();

#pragma unroll
        for (int mt = 0; mt < 4; ++mt) {
            f32x4 a0 = {0.f, 0.f, 0.f, 0.f};
#pragma unroll
            for (int kt = 0; kt < 4; ++kt) {
                us8 a = ld8(&H3[mt * 16 + c16][kt * 32 + hk * 8]);
                a0 = mfma16(a, w2f[kt], a0);
            }
#pragma unroll
            for (int j = 0; j < 4; ++j) {
                int row = mt * 16 + hk * 4 + j;
                int gn  = n0 + row;
                if (gn < NN)
                    out_x[(size_t)gn * 64 + w * 16 + c16] = a0[j] + b2v;
            }
        }
        __syncthreads();
    }
}

// ---------------------------------------------------------------- global update (fp32)
__global__ __launch_bounds__(128) void global_kernel(
    const float* __restrict__ uu,
    const float* __restrict__ g_w1, const float* __restrict__ g_b1,
    const float* __restrict__ g_w2, const float* __restrict__ g_b2,
    const float* __restrict__ out_x, const int* __restrict__ graphoff,
    float* __restrict__ out_u)
{
    const int g = blockIdx.x;
    const int t = threadIdx.x;
    __shared__ float gin[80];
    __shared__ float red[128];
    __shared__ float h[128];
    const int beg = graphoff[g], end = graphoff[g + 1];
    const int col = t & 63, half = t >> 6;
    float acc = 0.f;
    for (int n = beg + half; n < end; n += 2) acc += out_x[(size_t)n * 64 + col];
    red[t] = acc;
    __syncthreads();
    if (t < 64) {
        float c = fmaxf((float)(end - beg), 1.0f);
        gin[16 + t] = (red[t] + red[t + 64]) / c;
    } else if (t >= 112) {
        gin[t - 112] = uu[g * 16 + (t - 112)];
    }
    __syncthreads();
    float a = g_b1[t];
    for (int k = 0; k < 80; ++k) a += gin[k] * g_w1[k * 128 + t];
    h[t] = fmaxf(a, 0.f);
    __syncthreads();
    if (t < 32) {
        float a2 = g_b2[t];
        for (int k = 0; k < 128; ++k) a2 += h[k] * g_w2[k * 32 + t];
        out_u[g * 32 + t] = a2;
    }
}

extern "C" void kernel_launch(void* const* d_in, const int* in_sizes, int n_in,
                              void* d_out, int out_size, void* d_ws, size_t ws_size,
                              hipStream_t stream)
{
    const float* x     = (const float*)d_in[0];
    const float* ea    = (const float*)d_in[1];
    const float* uu    = (const float*)d_in[2];
    const float* e_w1  = (const float*)d_in[3];
    const float* e_b1  = (const float*)d_in[4];
    const float* e_w2  = (const float*)d_in[5];
    const float* e_b2  = (const float*)d_in[6];
    const float* n1_w1 = (const float*)d_in[7];
    const float* n1_b1 = (const float*)d_in[8];
    const float* n1_w2 = (const float*)d_in[9];
    const float* n1_b2 = (const float*)d_in[10];
    const float* n2_w1 = (const float*)d_in[11];
    const float* n2_b1 = (const float*)d_in[12];
    const float* n2_w2 = (const float*)d_in[13];
    const float* n2_b2 = (const float*)d_in[14];
    const float* g_w1  = (const float*)d_in[15];
    const float* g_b1  = (const float*)d_in[16];
    const float* g_w2  = (const float*)d_in[17];
    const float* g_b2  = (const float*)d_in[18];
    const int* eidx  = (const int*)d_in[19];
    const int* batch = (const int*)d_in[20];

    float* out_x = (float*)d_out;
    float* out_e = out_x + (size_t)NN * 64;
    float* out_u = out_e + (size_t)NE * 64;

    // ws: aggsum f32[NN*128] | deg[NN] | gcount[NG] | cursor[NN] | graphoff[260] |
    //     btot[64] | boff[64] | rec int4[NE] | xbf us[NN*64] | ubf us[NG*16] |
    //     packs us[200*512] | [ea_s us[NE*32] gated]
    float* aggsum   = (float*)d_ws;
    int*   deg      = (int*)(aggsum + (size_t)NN * 128);
    int*   gcount   = deg + NN;
    int*   cursor   = gcount + NG;
    int*   graphoff = cursor + NN;
    int*   btot     = graphoff + 260;
    int*   boff     = btot + 64;
    int4*  rec      = (int4*)(boff + 64);     // byte offset divisible by 16
    us*    xbf      = (us*)(rec + NE);
    us*    ubf      = xbf + (size_t)NN * 64;
    us*    packs    = ubf + (size_t)NG * 16;
    us*    wend     = packs + (size_t)200 * 512;
    size_t used     = (size_t)((char*)wend - (char*)d_ws);
    us* ea_s = nullptr;
    if (used + (size_t)NE * 32 * 2 <= ws_size) ea_s = wend;

    size_t zbytes = (size_t)NN * 128 * sizeof(float) + (NN + NG) * sizeof(int);
    hipMemsetAsync(d_ws, 0, zbytes, stream);

    hipLaunchKernelGGL(pack_kernel, dim3(200), dim3(512), 0, stream,
        e_w1, e_w2, n1_w1, n1_w2, n2_w1, n2_w2, packs);
    hipLaunchKernelGGL(prep_kernel, dim3(512), dim3(256), 0, stream,
        x, uu, eidx, batch, xbf, ubf, deg, gcount);
    hipLaunchKernelGGL(scanA_kernel, dim3(NB), dim3(1024), 0, stream, deg, btot);
    hipLaunchKernelGGL(scanB_kernel, dim3(1), dim3(256), 0, stream,
        btot, gcount, boff, graphoff);
    hipLaunchKernelGGL(scanC_kernel, dim3(NB), dim3(1024), 0, stream, deg, boff, cursor);
    hipLaunchKernelGGL(scatter_kernel, dim3(1024), dim3(256), 0, stream,
        eidx, batch, ea, cursor, rec, ea_s);
    hipLaunchKernelGGL(edge_kernel, dim3(768), dim3(256), 0, stream,
        xbf, ea, ubf, e_b1, e_b2, n1_b1, n1_b2, rec, ea_s, packs, out_e, aggsum);
    hipLaunchKernelGGL(node_kernel, dim3(782), dim3(256), 0, stream,
        xbf, ubf, n2_b1, n2_b2, batch, aggsum, deg, packs, out_x);
    hipLaunchKernelGGL(global_kernel, dim3(NG), dim3(128), 0, stream,
        uu, g_w1, g_b1, g_w2, g_b2, out_x, graphoff, out_u);
}